// Round 4
// baseline (383.603 us; speedup 1.0000x reference)
//
#include <hip/hip_runtime.h>
#include <utility>

// ---------------------------------------------------------------------------
// Compile-time Clebsch-Gordan coefficients (Racah formula), fp64 -> fp32.
// Split into 4 tables (one per l1) to stay under clang's constexpr step limit.
// ---------------------------------------------------------------------------
namespace cg {

constexpr double FACT[14] = {
  1.0, 1.0, 2.0, 6.0, 24.0, 120.0, 720.0, 5040.0, 40320.0, 362880.0,
  3628800.0, 39916800.0, 479001600.0, 6227020800.0
};

constexpr double csqrt(double x){
  double g = x > 1.0 ? x : 1.0;
  for (int i = 0; i < 64; ++i) g = 0.5 * (g + x / g);
  return g;
}
constexpr int cabs_(int x){ return x < 0 ? -x : x; }
constexpr int imax_(int a, int b){ return a > b ? a : b; }
constexpr int imin_(int a, int b){ return a < b ? a : b; }

constexpr double cg_coeff(int j1,int m1,int j2,int m2,int j,int m){
  if (m1 + m2 != m || j < cabs_(j1 - j2) || j > j1 + j2) return 0.0;
  double pre = csqrt((2.0*j + 1.0) * FACT[j1+j2-j] * FACT[j+j1-j2] * FACT[j+j2-j1]
                     / FACT[j1+j2+j+1]);
  pre *= csqrt(FACT[j+m] * FACT[j-m] * FACT[j1+m1] * FACT[j1-m1]
             * FACT[j2+m2] * FACT[j2-m2]);
  double s = 0.0;
  for (int k = 0; k <= j1 + j2 - j; ++k){
    int d2 = j1 - m1 - k, d3 = j2 + m2 - k, d4 = j - j2 + m1 + k, d5 = j - j1 - m2 + k;
    if (d2 < 0 || d3 < 0 || d4 < 0 || d5 < 0) continue;
    double denom = FACT[k] * FACT[j1+j2-j-k] * FACT[d2] * FACT[d3] * FACT[d4] * FACT[d5];
    s += ((k & 1) ? -1.0 : 1.0) / denom;
  }
  return pre * s;
}

struct Tab1 { float c[4][7][7][7]; };  // [l2][l][m1+l1][m2+l2] for fixed l1
constexpr Tab1 make_tab1(int l1){
  Tab1 t{};
  for (int l2 = 0; l2 < 4; ++l2)
    for (int l = 0; l < 7; ++l)
      for (int i1 = 0; i1 < 2*l1 + 1; ++i1)
        for (int i2 = 0; i2 < 2*l2 + 1; ++i2){
          int m1 = i1 - l1, m2 = i2 - l2, m = m1 + m2;
          if (m < -l || m > l) continue;
          t.c[l2][l][i1][i2] = (float)cg_coeff(l1, m1, l2, m2, l, m);
        }
  return t;
}
constexpr Tab1 T0 = make_tab1(0);
constexpr Tab1 T1 = make_tab1(1);
constexpr Tab1 T2 = make_tab1(2);
constexpr Tab1 T3 = make_tab1(3);
constexpr float getc(int l1,int l2,int l,int i1,int i2){
  return l1 == 0 ? T0.c[l2][l][i1][i2]
       : l1 == 1 ? T1.c[l2][l][i1][i2]
       : l1 == 2 ? T2.c[l2][l][i1][i2]
       :           T3.c[l2][l][i1][i2];
}

// Fragment (l1,l2) pair lists in gelib order (l1-major), per output l.
constexpr int NP[7]    = {4, 9, 11, 10, 6, 3, 1};          // tau_l
constexpr int IOFF[4]  = {0, 1, 4, 9};                     // input offset per l (pair units)
constexpr int P1[7][11] = {
  {0,1,2,3,0,0,0,0,0,0,0},
  {0,1,1,1,2,2,2,3,3,0,0},
  {0,1,1,1,2,2,2,2,3,3,3},
  {0,1,1,2,2,2,3,3,3,3,0},
  {1,2,2,3,3,3,0,0,0,0,0},
  {2,3,3,0,0,0,0,0,0,0,0},
  {3,0,0,0,0,0,0,0,0,0,0}
};
constexpr int P2[7][11] = {
  {0,1,2,3,0,0,0,0,0,0,0},
  {1,0,1,2,1,2,3,2,3,0,0},
  {2,1,2,3,0,1,2,3,1,2,3},
  {3,2,3,1,2,3,0,1,2,3,0},
  {3,2,3,1,2,3,0,0,0,0,0},
  {3,2,3,0,0,0,0,0,0,0,0},
  {3,0,0,0,0,0,0,0,0,0,0}
};

// ---- Row table: 49 output rows (l, mi), each 2*NP[l] floats, consecutive. ----
constexpr int ROWN = 49;
struct Rows { int l[ROWN]; int mi[ROWN]; int off[ROWN]; int sz[ROWN]; };
constexpr Rows make_rows(){
  Rows r{}; int idx = 0; int off = 0;
  for (int l = 0; l < 7; ++l)
    for (int mi = 0; mi < 2*l + 1; ++mi){
      r.l[idx] = l; r.mi[idx] = mi; r.off[idx] = off; r.sz[idx] = 2*NP[l];
      off += 2*NP[l]; ++idx;
    }
  return r;
}
constexpr Rows RW = make_rows();

// ---- Flat map: global float index g (0..511) -> (l, mi, t, re/im). ----
struct OutMap { int l[512]; int mi[512]; int t[512]; int ri[512]; };
constexpr OutMap make_outmap(){
  OutMap om{}; int g = 0;
  for (int r = 0; r < ROWN; ++r)
    for (int p = 0; p < RW.sz[r]; ++p){
      om.l[g] = RW.l[r]; om.mi[g] = RW.mi[r]; om.t[g] = p / 2; om.ri[g] = p & 1; ++g;
    }
  return om;
}
constexpr OutMap OM = make_outmap();

} // namespace cg

// ---------------------------------------------------------------------------
// static_for: guarantees every loop index is a compile-time constant
// ---------------------------------------------------------------------------
template<class F, int... Is>
__device__ __forceinline__ void sfor_impl(F&& f, std::integer_sequence<int, Is...>){
  (f(std::integral_constant<int, Is>{}), ...);
}
template<int N, class F>
__device__ __forceinline__ void sfor(F&& f){
  sfor_impl(static_cast<F&&>(f), std::make_integer_sequence<int, N>{});
}

// ---------------------------------------------------------------------------
// Compute floats [SEG*16 + JSUB*4, +4) of one element's 512-float output and
// store them as a single dwordx4 (16B) — 4 lanes (JSUB=0..3) complete a 64B
// line with 4 adjacent store instructions, so L2 merges to full-line writes.
// ---------------------------------------------------------------------------
template<int SEG, int JSUB>
__device__ __forceinline__ void store_quarter(const float (&xr)[16], const float (&xi)[16],
                                              float* __restrict__ o){
  float v[4];
  sfor<4>([&](auto IC){
    constexpr int i  = decltype(IC)::value;
    constexpr int g  = SEG * 16 + JSUB * 4 + i;
    constexpr int l  = cg::OM.l[g];
    constexpr int mi = cg::OM.mi[g];
    constexpr int t  = cg::OM.t[g];
    constexpr int ri = cg::OM.ri[g];
    constexpr int l1 = cg::P1[l][t];
    constexpr int l2 = cg::P2[l][t];
    constexpr int m  = mi - l;
    constexpr int m1lo = cg::imax_(-l1, m - l2);
    constexpr int m1hi = cg::imin_( l1, m + l2);
    float acc = 0.f;
    sfor<m1hi - m1lo + 1>([&](auto KC){
      constexpr int m1 = m1lo + decltype(KC)::value;
      constexpr int m2 = m - m1;
      constexpr float c = cg::getc(l1, l2, l, m1 + l1, m2 + l2);
      if constexpr (c != 0.0f){
        constexpr int ia = cg::IOFF[l1] + m1 + l1;
        constexpr int ib = cg::IOFF[l2] + m2 + l2;
        float term;
        if constexpr (ri == 0) term = fmaf(-xi[ia], xi[ib], xr[ia] * xr[ib]);  // re
        else                   term = fmaf( xi[ia], xr[ib], xr[ia] * xi[ib]);  // im
        acc = fmaf(c, term, acc);
      }
    });
    v[i] = acc;
  });
  float4 f4; f4.x = v[0]; f4.y = v[1]; f4.z = v[2]; f4.w = v[3];
  *reinterpret_cast<float4*>(o + SEG * 16 + JSUB * 4) = f4;
}

// ---------------------------------------------------------------------------
// Wave = 16 elements. lane = jsub*16 + esub: 4 lanes cooperate per element
// (one 16B quarter-line each). No LDS, no barriers; waves fully independent.
// ---------------------------------------------------------------------------
__global__ __launch_bounds__(256) void cgprod_kernel(
    const float* __restrict__ x0, const float* __restrict__ x1,
    const float* __restrict__ x2, const float* __restrict__ x3,
    float* __restrict__ out, int B)
{
  const int lane  = threadIdx.x & 63;
  const int wv    = threadIdx.x >> 6;
  const int jsub  = lane >> 4;   // which 16B quarter of each 64B segment
  const int esub  = lane & 15;   // which element within the wave's 16
  const int e     = blockIdx.x * 64 + wv * 16 + esub;
  if (e >= B) return;            // no barriers -> safe early exit

  float xr[16], xi[16];  // per-l pair offsets 0,1,4,9 (sizes 1,3,5,7)
  { float2 v = *reinterpret_cast<const float2*>(x0 + (size_t)e * 2);
    xr[0] = v.x; xi[0] = v.y; }
  { const float2* p = reinterpret_cast<const float2*>(x1 + (size_t)e * 6);
    sfor<3>([&](auto I){ constexpr int i = decltype(I)::value;
      float2 v = p[i]; xr[1+i] = v.x; xi[1+i] = v.y; }); }
  { const float2* p = reinterpret_cast<const float2*>(x2 + (size_t)e * 10);
    sfor<5>([&](auto I){ constexpr int i = decltype(I)::value;
      float2 v = p[i]; xr[4+i] = v.x; xi[4+i] = v.y; }); }
  { const float2* p = reinterpret_cast<const float2*>(x3 + (size_t)e * 14);
    sfor<7>([&](auto I){ constexpr int i = decltype(I)::value;
      float2 v = p[i]; xr[9+i] = v.x; xi[9+i] = v.y; }); }

  float* o = out + (size_t)e * 512;

  // Segment-outer / quarter-inner: the 4 exec-masked cases of each segment
  // issue their 16B stores back-to-back, completing each 64B line within
  // ~4 instructions (tiny partial-line working set -> full-line HBM writes).
  sfor<32>([&](auto SC){
    constexpr int seg = decltype(SC)::value;
    switch (jsub){
      case 0:  store_quarter<seg, 0>(xr, xi, o); break;
      case 1:  store_quarter<seg, 1>(xr, xi, o); break;
      case 2:  store_quarter<seg, 2>(xr, xi, o); break;
      default: store_quarter<seg, 3>(xr, xi, o); break;
    }
  });
}

extern "C" void kernel_launch(void* const* d_in, const int* in_sizes, int n_in,
                              void* d_out, int out_size, void* d_ws, size_t ws_size,
                              hipStream_t stream)
{
  const float* x0 = (const float*)d_in[0];
  const float* x1 = (const float*)d_in[1];
  const float* x2 = (const float*)d_in[2];
  const float* x3 = (const float*)d_in[3];
  float* out = (float*)d_out;

  const int B = in_sizes[0] / 2;  // x0 is (B, 1, 2)
  const int block = 256;          // 4 waves x 16 elements = 64 elements/block
  const int grid = (B + 63) / 64;
  cgprod_kernel<<<grid, block, 0, stream>>>(x0, x1, x2, x3, out, B);
}